// Round 6
// baseline (1183.033 us; speedup 1.0000x reference)
//
#include <hip/hip_runtime.h>
#include <math.h>

typedef unsigned short ushort_t;
typedef __bf16 bf16x8 __attribute__((ext_vector_type(8)));
typedef __bf16 bf16x4 __attribute__((ext_vector_type(4)));
typedef float f32x4 __attribute__((ext_vector_type(4)));

#define TWO_PI_F 6.283185307179586f

// ---- ws float-offset layout ----
#define WMT_OFF   0         // [296][512] f32 W_mod^T
#define PC_OFF    151552    // [1024][512] f32 per-b modulation constants
#define WT0P_OFF  675840    // 40960 ushort: GEMM0 W-frags [5 ks][16 nt][64 l][8 j]
#define WT1P_OFF  696320    // 98304 ushort: GEMM1 W-frags [12 ks][16 nt][64 l][8 j]

__device__ __forceinline__ ushort_t f2bf(float f) {
  unsigned int u = __float_as_uint(f);
  u += 0x7fffu + ((u >> 16) & 1u);
  return (ushort_t)(u >> 16);
}

// ---------------- pack: W_mod^T (f32) + MFMA W-fragment panels (bf16) ----------------
__global__ void pack_mfma_k(const float* __restrict__ W0,
                            const float* __restrict__ W1,
                            const float* __restrict__ W_mod,
                            float* __restrict__ WmT,
                            ushort_t* __restrict__ WT0p,
                            ushort_t* __restrict__ WT1p) {
  int i0 = blockIdx.x * blockDim.x + threadIdx.x;
  int stride = gridDim.x * blockDim.x;
  for (int idx = i0; idx < 296 * 512; idx += stride) {
    int c = idx >> 9, m = idx & 511;
    WmT[idx] = W_mod[m * 296 + c];
  }
  for (int e = i0; e < 40960; e += stride) {
    int j = e & 7, l = (e >> 3) & 63, nt = (e >> 9) & 15, ks = e >> 13;
    int k = ks * 32 + (l >> 4) * 8 + j;
    int n = nt * 16 + (l & 15);
    float v = 0.0f;
    if (k < 17) v = W0[n * 17 + k];
    else if (k >= 32) v = W_mod[n * 296 + 128 + (k - 32)];
    WT0p[e] = f2bf(v);
  }
  for (int e = i0; e < 98304; e += stride) {
    int j = e & 7, l = (e >> 3) & 63, nt = (e >> 9) & 15, ks = e >> 13;
    int k = ks * 32 + (l >> 4) * 8 + j;
    int n = nt * 16 + (l & 15);
    float v = (k < 256) ? W1[n * 256 + k]
                        : W_mod[(256 + n) * 296 + 128 + (k - 256)];
    WT1p[e] = f2bf(v);
  }
}

// ---------------- static encoder + per-b modulation consts (verified R1-R5) ----------------
__global__ void precompute_pc_k(const float* __restrict__ code,
                                const float* __restrict__ x_statics,
                                const int* __restrict__ dir_idx,
                                const float* __restrict__ WmT,
                                const float* __restrict__ b_mod,
                                const float* __restrict__ b0,
                                const float* __restrict__ b1,
                                const float* __restrict__ Bmat,
                                const float* __restrict__ Ws1,
                                const float* __restrict__ bs1,
                                const float* __restrict__ Ws2,
                                const float* __restrict__ bs2,
                                const float* __restrict__ dir_emb,
                                float* __restrict__ pc) {
  int b = blockIdx.x, t = threadIdx.x;  // 512 threads
  __shared__ float feats[32];
  __shared__ float h[64];
  __shared__ float se[40];
  __shared__ float cd[128];
  if (t < 16) {
    float p = TWO_PI_F * (x_statics[2 * b] * Bmat[t] + x_statics[2 * b + 1] * Bmat[16 + t]);
    feats[t] = sinf(p);
    feats[16 + t] = cosf(p);
  }
  if (t >= 128 && t < 256) cd[t - 128] = code[b * 128 + (t - 128)];
  __syncthreads();
  if (t < 64) {
    float a = bs1[t];
#pragma unroll
    for (int c = 0; c < 32; ++c) a = fmaf(feats[c], Ws1[t * 32 + c], a);
    h[t] = 0.5f * a * (1.0f + erff(a * 0.70710678118654752440f));
  }
  __syncthreads();
  if (t < 32) {
    float a = bs2[t];
#pragma unroll
    for (int c = 0; c < 64; ++c) a = fmaf(h[c], Ws2[t * 64 + c], a);
    se[t] = a;
  } else if (t < 40) {
    se[t] = dir_emb[dir_idx[b] * 8 + (t - 32)];
  }
  __syncthreads();
  float a = b_mod[t] + ((t < 256) ? b0[t] : b1[t - 256]);
  for (int c = 0; c < 128; ++c) a = fmaf(cd[c], WmT[c * 512 + t], a);
#pragma unroll
  for (int c = 0; c < 40; ++c) a = fmaf(se[c], WmT[(256 + c) * 512 + t], a);
  pc[b * 512 + t] = a;
}

// ---------------- main: MFMA FiLM MLP, 128-row blocks ----------------
// grid = 4096 (128 rows each), block = 512 = 8 waves as 2 row-groups x 4 col-groups;
// wave tile 64 rows x 64 cols (acc 4x4 f32x4 = 64 VGPR). 2 blocks/CU (68KB LDS),
// __launch_bounds__(512,4) -> <=128 VGPR.
// hs is NOT staged in LDS: B-frags gathered from global f32 (16 rows x full 128B
// line per wave-instr; GEMM1 re-read hits L2). pos built in registers.
// x0 LDS layout [kchunk 8][row 128][64B], XOR-swizzle ((row&7)<<4) applied to the
// base only (kchunk*8192 + mt*1024 offsets never carry into bits 4-6 -> imm-folds).
__global__ __launch_bounds__(512, 4) void film_mfma(
    const float* __restrict__ coords, const float* __restrict__ hs,
    const float* __restrict__ pc, const ushort_t* __restrict__ WT0p,
    const ushort_t* __restrict__ WT1p, const float* __restrict__ Wo,
    const float* __restrict__ bo, float* __restrict__ out) {
  __shared__ uint4 x0buf4[65536 / 16];
  __shared__ float pcs[512];
  __shared__ float psum[512];  // [wc 4][128 rows]
  char* x0buf = (char*)x0buf4;

  const int tid = threadIdx.x;
  const int wv = tid >> 6;
  const int l = tid & 63;
  const int l4 = l & 15;
  const int hi4 = l >> 4;
  const int wr = wv >> 2;   // row half 0/1
  const int wc = wv & 3;    // col quarter
  const size_t row0 = (size_t)blockIdx.x * 128;
  const int b = blockIdx.x >> 2;  // 4 blocks per b

  pcs[tid] = pc[(size_t)b * 512 + tid];

  const int rbase = wr * 64 + l4;  // block-local row for mt=0
  // hs gather pointer: lane reads hs[row0+rbase+mt*16][hi4*8 + kchunk*32 ..]
  const char* hp0 = (const char*)hs + (row0 + rbase) * 512 + hi4 * 32;
  const int swz = (rbase & 7) << 4;  // mt*16 doesn't change row&7
  const int xrd = (rbase * 64 + hi4 * 16) ^ swz;                 // x0 read base
  const int xw0 = (rbase * 64 + hi4 * 8) ^ swz;                  // x0 write base (i even)
  const int xw1 = (rbase * 64 + 32 + hi4 * 8) ^ swz;             // x0 write base (i odd)

  f32x4 acc[4][4];
#pragma unroll
  for (int mt = 0; mt < 4; ++mt)
#pragma unroll
    for (int i = 0; i < 4; ++i) acc[mt][i] = (f32x4){0.f, 0.f, 0.f, 0.f};

  // ---------------- GEMM0: K=160 (ks0 = pos in-reg, ks1..4 = hs gather) ----------------
  {
    const uint4* Bb = (const uint4*)WT0p;
#pragma unroll
    for (int ks = 0; ks < 5; ++ks) {
      bf16x8 w[4];
#pragma unroll
      for (int i = 0; i < 4; ++i)
        w[i] = __builtin_bit_cast(bf16x8, Bb[(ks * 16 + wc * 4 + i) * 64 + l]);
#pragma unroll
      for (int mt = 0; mt < 4; ++mt) {
        bf16x8 u;
        if (ks == 0) {
          float c = coords[row0 + rbase + mt * 16];
#pragma unroll
          for (int j = 0; j < 8; ++j) u[j] = (__bf16)0.0f;
          if (hi4 == 0) {
            u[0] = (__bf16)c;
#pragma unroll
            for (int f = 1; f < 7; ++f) u[1 + f] = (__bf16)__sinf(1.25f * (float)f * c);
          } else if (hi4 == 1) {
            u[0] = (__bf16)__sinf(8.75f * c);
            u[1] = (__bf16)1.0f;
#pragma unroll
            for (int f = 1; f < 7; ++f) u[1 + f] = (__bf16)__cosf(1.25f * (float)f * c);
          } else if (hi4 == 2) {
            u[0] = (__bf16)__cosf(8.75f * c);
          }
        } else {
          float4 f0 = *(const float4*)(hp0 + mt * 8192 + (ks - 1) * 128);
          float4 f1 = *(const float4*)(hp0 + mt * 8192 + (ks - 1) * 128 + 16);
          u[0] = (__bf16)f0.x; u[1] = (__bf16)f0.y; u[2] = (__bf16)f0.z; u[3] = (__bf16)f0.w;
          u[4] = (__bf16)f1.x; u[5] = (__bf16)f1.y; u[6] = (__bf16)f1.z; u[7] = (__bf16)f1.w;
        }
#pragma unroll
        for (int i = 0; i < 4; ++i)
          acc[mt][i] = __builtin_amdgcn_mfma_f32_16x16x32_bf16(w[i], u, acc[mt][i], 0, 0, 0);
      }
    }
  }
  __syncthreads();  // pcs visible; x0buf untouched so far

  // ---- epilogue0: relu(acc + pc0) -> x0 bf16 to LDS [n>>5][row][ (n&31)*2 ] ----
#pragma unroll
  for (int i = 0; i < 4; ++i) {
    int n0 = wc * 64 + i * 16 + hi4 * 4;
    float4 p4 = *(const float4*)&pcs[n0];
    int wb = ((i & 1) ? xw1 : xw0) + (wc * 2 + (i >> 1)) * 8192;
#pragma unroll
    for (int mt = 0; mt < 4; ++mt) {
      bf16x4 hv;
      hv[0] = (__bf16)fmaxf(acc[mt][i][0] + p4.x, 0.f);
      hv[1] = (__bf16)fmaxf(acc[mt][i][1] + p4.y, 0.f);
      hv[2] = (__bf16)fmaxf(acc[mt][i][2] + p4.z, 0.f);
      hv[3] = (__bf16)fmaxf(acc[mt][i][3] + p4.w, 0.f);
      *(uint2*)(x0buf + wb + mt * 1024) = __builtin_bit_cast(uint2, hv);
    }
  }
  __syncthreads();

#pragma unroll
  for (int mt = 0; mt < 4; ++mt)
#pragma unroll
    for (int i = 0; i < 4; ++i) acc[mt][i] = (f32x4){0.f, 0.f, 0.f, 0.f};

  // ---------------- GEMM1: K=384 (ks0..7 = x0 from LDS, ks8..11 = hs gather) ----------------
  {
    const uint4* Bb = (const uint4*)WT1p;
#pragma unroll
    for (int ks = 0; ks < 12; ++ks) {
      bf16x8 w[4];
#pragma unroll
      for (int i = 0; i < 4; ++i)
        w[i] = __builtin_bit_cast(bf16x8, Bb[(ks * 16 + wc * 4 + i) * 64 + l]);
#pragma unroll
      for (int mt = 0; mt < 4; ++mt) {
        bf16x8 u;
        if (ks < 8) {
          __builtin_memcpy(&u, x0buf + xrd + ks * 8192 + mt * 1024, 16);
        } else {
          float4 f0 = *(const float4*)(hp0 + mt * 8192 + (ks - 8) * 128);
          float4 f1 = *(const float4*)(hp0 + mt * 8192 + (ks - 8) * 128 + 16);
          u[0] = (__bf16)f0.x; u[1] = (__bf16)f0.y; u[2] = (__bf16)f0.z; u[3] = (__bf16)f0.w;
          u[4] = (__bf16)f1.x; u[5] = (__bf16)f1.y; u[6] = (__bf16)f1.z; u[7] = (__bf16)f1.w;
        }
#pragma unroll
        for (int i = 0; i < 4; ++i)
          acc[mt][i] = __builtin_amdgcn_mfma_f32_16x16x32_bf16(w[i], u, acc[mt][i], 0, 0, 0);
      }
    }
  }

  // ---- epilogue1: relu(acc + pc1) . Wo; reduce over 16 n per lane + 2 shfl ----
  {
    float4 p4[4], w4[4];
#pragma unroll
    for (int i = 0; i < 4; ++i) {
      int n0 = wc * 64 + i * 16 + hi4 * 4;
      p4[i] = *(const float4*)&pcs[256 + n0];
      w4[i] = ((const float4*)Wo)[(wc * 4 + i) * 4 + hi4];
    }
#pragma unroll
    for (int mt = 0; mt < 4; ++mt) {
      float s = 0.f;
#pragma unroll
      for (int i = 0; i < 4; ++i) {
        s += fmaxf(acc[mt][i][0] + p4[i].x, 0.f) * w4[i].x;
        s += fmaxf(acc[mt][i][1] + p4[i].y, 0.f) * w4[i].y;
        s += fmaxf(acc[mt][i][2] + p4[i].z, 0.f) * w4[i].z;
        s += fmaxf(acc[mt][i][3] + p4[i].w, 0.f) * w4[i].w;
      }
      s += __shfl_xor(s, 16);
      s += __shfl_xor(s, 32);
      if (hi4 == 0) psum[wc * 128 + rbase + mt * 16] = s;
    }
  }
  __syncthreads();
  if (tid < 128) {
    float s = bo[0] + psum[tid] + psum[128 + tid] + psum[256 + tid] + psum[384 + tid];
    out[row0 + tid] = s;
  }
}

extern "C" void kernel_launch(void* const* d_in, const int* in_sizes, int n_in,
                              void* d_out, int out_size, void* d_ws, size_t ws_size,
                              hipStream_t stream) {
  (void)in_sizes; (void)n_in; (void)out_size; (void)ws_size;
  const float* coords    = (const float*)d_in[0];
  const float* code      = (const float*)d_in[1];
  const float* hs        = (const float*)d_in[2];
  const float* x_statics = (const float*)d_in[3];
  const int*   dir_idx   = (const int*)d_in[4];
  const float* W_mod     = (const float*)d_in[5];
  const float* b_mod     = (const float*)d_in[6];
  const float* W0        = (const float*)d_in[7];
  const float* b0        = (const float*)d_in[8];
  const float* W1        = (const float*)d_in[9];
  const float* b1        = (const float*)d_in[10];
  const float* Wo        = (const float*)d_in[11];
  const float* bo        = (const float*)d_in[12];
  const float* Bmat      = (const float*)d_in[13];
  const float* Ws1       = (const float*)d_in[14];
  const float* bs1       = (const float*)d_in[15];
  const float* Ws2       = (const float*)d_in[16];
  const float* bs2       = (const float*)d_in[17];
  const float* dir_emb   = (const float*)d_in[18];
  float* out = (float*)d_out;
  float* wsf = (float*)d_ws;

  float*    WmT  = wsf + WMT_OFF;
  float*    pc   = wsf + PC_OFF;
  ushort_t* WT0p = (ushort_t*)(wsf + WT0P_OFF);
  ushort_t* WT1p = (ushort_t*)(wsf + WT1P_OFF);

  hipLaunchKernelGGL(pack_mfma_k, dim3(1024), dim3(256), 0, stream,
                     W0, W1, W_mod, WmT, WT0p, WT1p);
  hipLaunchKernelGGL(precompute_pc_k, dim3(1024), dim3(512), 0, stream,
                     code, x_statics, dir_idx, WmT, b_mod, b0, b1,
                     Bmat, Ws1, bs1, Ws2, bs2, dir_emb, pc);
  hipLaunchKernelGGL(film_mfma, dim3(4096), dim3(512), 0, stream,
                     coords, hs, pc, WT0p, WT1p, Wo, bo, out);
}

// Round 7
// 193.107 us; speedup vs baseline: 6.1263x; 6.1263x over previous
//
#include <hip/hip_runtime.h>
#include <math.h>

typedef unsigned short ushort_t;
typedef __bf16 bf16x8 __attribute__((ext_vector_type(8)));
typedef __bf16 bf16x4 __attribute__((ext_vector_type(4)));
typedef float f32x4 __attribute__((ext_vector_type(4)));

#define TWO_PI_F 6.283185307179586f

// ---- ws float-offset layout ----
#define WMT_OFF   0         // [296][512] f32 W_mod^T
#define PC_OFF    151552    // [1024][512] f32 per-b modulation constants
#define WT0P_OFF  675840    // 40960 ushort: GEMM0 W-frags [5 ks][16 nt][64 l][8 j]
#define WT1P_OFF  696320    // 98304 ushort: GEMM1 W-frags [12 ks][16 nt][64 l][8 j]

__device__ __forceinline__ ushort_t f2bf(float f) {
  unsigned int u = __float_as_uint(f);
  u += 0x7fffu + ((u >> 16) & 1u);
  return (ushort_t)(u >> 16);
}

// ---------------- pack: W_mod^T (f32) + MFMA W-fragment panels (bf16) ----------------
__global__ void pack_mfma_k(const float* __restrict__ W0,
                            const float* __restrict__ W1,
                            const float* __restrict__ W_mod,
                            float* __restrict__ WmT,
                            ushort_t* __restrict__ WT0p,
                            ushort_t* __restrict__ WT1p) {
  int i0 = blockIdx.x * blockDim.x + threadIdx.x;
  int stride = gridDim.x * blockDim.x;
  for (int idx = i0; idx < 296 * 512; idx += stride) {
    int c = idx >> 9, m = idx & 511;
    WmT[idx] = W_mod[m * 296 + c];
  }
  for (int e = i0; e < 40960; e += stride) {
    int j = e & 7, l = (e >> 3) & 63, nt = (e >> 9) & 15, ks = e >> 13;
    int k = ks * 32 + (l >> 4) * 8 + j;
    int n = nt * 16 + (l & 15);
    float v = 0.0f;
    if (k < 17) v = W0[n * 17 + k];
    else if (k >= 32) v = W_mod[n * 296 + 128 + (k - 32)];
    WT0p[e] = f2bf(v);
  }
  for (int e = i0; e < 98304; e += stride) {
    int j = e & 7, l = (e >> 3) & 63, nt = (e >> 9) & 15, ks = e >> 13;
    int k = ks * 32 + (l >> 4) * 8 + j;
    int n = nt * 16 + (l & 15);
    float v = (k < 256) ? W1[n * 256 + k]
                        : W_mod[(256 + n) * 296 + 128 + (k - 256)];
    WT1p[e] = f2bf(v);
  }
}

// ---------------- static encoder + per-b modulation consts (verified R1-R6) ----------------
__global__ void precompute_pc_k(const float* __restrict__ code,
                                const float* __restrict__ x_statics,
                                const int* __restrict__ dir_idx,
                                const float* __restrict__ WmT,
                                const float* __restrict__ b_mod,
                                const float* __restrict__ b0,
                                const float* __restrict__ b1,
                                const float* __restrict__ Bmat,
                                const float* __restrict__ Ws1,
                                const float* __restrict__ bs1,
                                const float* __restrict__ Ws2,
                                const float* __restrict__ bs2,
                                const float* __restrict__ dir_emb,
                                float* __restrict__ pc) {
  int b = blockIdx.x, t = threadIdx.x;  // 512 threads
  __shared__ float feats[32];
  __shared__ float h[64];
  __shared__ float se[40];
  __shared__ float cd[128];
  if (t < 16) {
    float p = TWO_PI_F * (x_statics[2 * b] * Bmat[t] + x_statics[2 * b + 1] * Bmat[16 + t]);
    feats[t] = sinf(p);
    feats[16 + t] = cosf(p);
  }
  if (t >= 128 && t < 256) cd[t - 128] = code[b * 128 + (t - 128)];
  __syncthreads();
  if (t < 64) {
    float a = bs1[t];
#pragma unroll
    for (int c = 0; c < 32; ++c) a = fmaf(feats[c], Ws1[t * 32 + c], a);
    h[t] = 0.5f * a * (1.0f + erff(a * 0.70710678118654752440f));
  }
  __syncthreads();
  if (t < 32) {
    float a = bs2[t];
#pragma unroll
    for (int c = 0; c < 64; ++c) a = fmaf(h[c], Ws2[t * 64 + c], a);
    se[t] = a;
  } else if (t < 40) {
    se[t] = dir_emb[dir_idx[b] * 8 + (t - 32)];
  }
  __syncthreads();
  float a = b_mod[t] + ((t < 256) ? b0[t] : b1[t - 256]);
  for (int c = 0; c < 128; ++c) a = fmaf(cd[c], WmT[c * 512 + t], a);
#pragma unroll
  for (int c = 0; c < 40; ++c) a = fmaf(se[c], WmT[(256 + c) * 512 + t], a);
  pc[b * 512 + t] = a;
}

// ---------------- main: MFMA FiLM MLP, 128-row blocks, 64x64 wave tiles ----------------
// grid = 4096 (128 rows), block = 512 = 8 waves (wr = row half, wc = col quarter).
// Wave tile 64 rows x 64 cols: acc[4][4] f32x4 = 64 VGPR.
// __launch_bounds__(512,2): 256-VGPR budget (R6's spill was (512,4)'s 128 cap).
// LDS 100.3KB -> 1 block/CU (2 waves/SIMD, HK-style residency); weight frags
// double-buffered from L2 to keep the MFMA pipe fed across the thin occupancy.
// rowbuf row (768B): [0,512)=x0, [512,768)=hs; 16B-chunk XOR-swizzle ((row&7)<<4).
// GEMM0 k-order {1,2,3,4,0}: pos chunk (bytes [0,64)) read last, then barrier,
// then epilogue0 overwrites [0,512) with x0; GEMM1 reads ks*64 for ks=0..11.
__global__ __launch_bounds__(512, 2) void film_mfma(
    const float* __restrict__ coords, const float* __restrict__ hs,
    const float* __restrict__ pc, const ushort_t* __restrict__ WT0p,
    const ushort_t* __restrict__ WT1p, const float* __restrict__ Wo,
    const float* __restrict__ bo, float* __restrict__ out) {
  __shared__ uint4 rowbuf4[98304 / 16];
  __shared__ float pcs[512];
  __shared__ float psum[512];  // [wc 4][row 128]
  char* rowbuf = (char*)rowbuf4;

  const int tid = threadIdx.x;
  const int wv = tid >> 6;
  const int l = tid & 63;
  const int l4 = l & 15;
  const int hi4 = l >> 4;
  const int wr = wv >> 2;   // row half 0/1
  const int wc = wv & 3;    // col quarter 0..3
  const size_t row0 = (size_t)blockIdx.x * 128;
  const int b = blockIdx.x >> 2;  // 4 blocks per b

  pcs[tid] = pc[(size_t)b * 512 + tid];

  // ---- stage hs -> rowbuf[row][512..768), bf16, swizzled ----
  {
    const float4* hsv = (const float4*)(hs + row0 * 128);
#pragma unroll
    for (int it = 0; it < 8; ++it) {
      int idx = it * 512 + tid;       // 4096 float4 = 128 rows x 32
      int r = idx >> 5, c4 = idx & 31;
      float4 v = hsv[idx];
      bf16x4 hb;
      hb[0] = (__bf16)v.x; hb[1] = (__bf16)v.y;
      hb[2] = (__bf16)v.z; hb[3] = (__bf16)v.w;
      int byte = (r * 768 + 512 + c4 * 8) ^ ((r & 7) << 4);
      *(uint2*)(rowbuf + byte) = __builtin_bit_cast(uint2, hb);
    }
  }
  // ---- stage pos -> rowbuf[row][0..64), bf16, pre-swizzled 16B chunks ----
  if (tid < 128) {
    int row = tid;
    float c = coords[row0 + row];
    __bf16 pv[32];
    pv[0] = (__bf16)c;
    pv[1] = (__bf16)0.0f;  // sin(0*c)
    pv[9] = (__bf16)1.0f;  // cos(0*c)
#pragma unroll
    for (int f = 1; f < 8; ++f) {
      float s, co;
      __sincosf(1.25f * (float)f * c, &s, &co);
      pv[1 + f] = (__bf16)s;
      pv[9 + f] = (__bf16)co;
    }
#pragma unroll
    for (int k = 17; k < 32; ++k) pv[k] = (__bf16)0.0f;
    int base = row * 768, swzp = (row & 7) << 4;
#pragma unroll
    for (int s = 0; s < 4; ++s)
      *(uint4*)(rowbuf + ((base + s * 16) ^ swzp)) = *(const uint4*)&pv[s * 8];
  }

  // per-mt LDS read addressing: row = wr*64 + mt*16 + l4; row&7 == l4&7 for all mt
  const int swz = (l4 & 7) << 4;
  int addrU[4];
#pragma unroll
  for (int mt = 0; mt < 4; ++mt)
    addrU[mt] = (wr * 64 + mt * 16 + l4) * 768 + hi4 * 16;

  __syncthreads();

  f32x4 acc[4][4];
#pragma unroll
  for (int mt = 0; mt < 4; ++mt)
#pragma unroll
    for (int i = 0; i < 4; ++i) acc[mt][i] = (f32x4){0.f, 0.f, 0.f, 0.f};

  // ---------------- GEMM0: K=160, k-chunk order {1,2,3,4,0}, W double-buffered ----------------
  {
    const uint4* Bb = (const uint4*)WT0p;
    bf16x8 wf[2][4];
#pragma unroll
    for (int i = 0; i < 4; ++i)
      wf[0][i] = __builtin_bit_cast(bf16x8, Bb[(1 * 16 + wc * 4 + i) * 64 + l]);
#pragma unroll
    for (int kk = 0; kk < 5; ++kk) {
      const int ks = (kk < 4) ? (kk + 1) : 0;
      const int cur = kk & 1;
      if (kk < 4) {
        const int ksn = (kk < 3) ? (kk + 2) : 0;
#pragma unroll
        for (int i = 0; i < 4; ++i)
          wf[cur ^ 1][i] = __builtin_bit_cast(bf16x8, Bb[(ksn * 16 + wc * 4 + i) * 64 + l]);
      }
#pragma unroll
      for (int mt = 0; mt < 4; ++mt) {
        bf16x8 u;
        int off = (ks == 0) ? addrU[mt] : (addrU[mt] + 512 + (ks - 1) * 64);
        __builtin_memcpy(&u, rowbuf + (off ^ swz), 16);
#pragma unroll
        for (int i = 0; i < 4; ++i)
          acc[mt][i] = __builtin_amdgcn_mfma_f32_16x16x32_bf16(wf[cur][i], u, acc[mt][i], 0, 0, 0);
      }
    }
  }
  __syncthreads();  // pos reads done before x0 overwrites [0,512)

  // ---- epilogue0: relu(acc + pc0) -> x0 bf16, packed b64 writes ----
#pragma unroll
  for (int i = 0; i < 4; ++i) {
    int n0 = wc * 64 + i * 16 + hi4 * 4;
    float4 p4 = *(const float4*)&pcs[n0];
#pragma unroll
    for (int mt = 0; mt < 4; ++mt) {
      int t = wr * 64 + mt * 16 + l4;
      bf16x4 hv;
      hv[0] = (__bf16)fmaxf(acc[mt][i][0] + p4.x, 0.f);
      hv[1] = (__bf16)fmaxf(acc[mt][i][1] + p4.y, 0.f);
      hv[2] = (__bf16)fmaxf(acc[mt][i][2] + p4.z, 0.f);
      hv[3] = (__bf16)fmaxf(acc[mt][i][3] + p4.w, 0.f);
      int byte = (t * 768 + n0 * 2) ^ ((t & 7) << 4);
      *(uint2*)(rowbuf + byte) = __builtin_bit_cast(uint2, hv);
    }
  }
  __syncthreads();

#pragma unroll
  for (int mt = 0; mt < 4; ++mt)
#pragma unroll
    for (int i = 0; i < 4; ++i) acc[mt][i] = (f32x4){0.f, 0.f, 0.f, 0.f};

  // ---------------- GEMM1: K=384 (x0 [0,512) then hs [512,768)), W double-buffered ----------------
  {
    const uint4* Bb = (const uint4*)WT1p;
    bf16x8 wf[2][4];
#pragma unroll
    for (int i = 0; i < 4; ++i)
      wf[0][i] = __builtin_bit_cast(bf16x8, Bb[(wc * 4 + i) * 64 + l]);
#pragma unroll
    for (int ks = 0; ks < 12; ++ks) {
      const int cur = ks & 1;
      if (ks < 11) {
#pragma unroll
        for (int i = 0; i < 4; ++i)
          wf[cur ^ 1][i] = __builtin_bit_cast(bf16x8, Bb[((ks + 1) * 16 + wc * 4 + i) * 64 + l]);
      }
#pragma unroll
      for (int mt = 0; mt < 4; ++mt) {
        bf16x8 u;
        __builtin_memcpy(&u, rowbuf + ((addrU[mt] + ks * 64) ^ swz), 16);
#pragma unroll
        for (int i = 0; i < 4; ++i)
          acc[mt][i] = __builtin_amdgcn_mfma_f32_16x16x32_bf16(wf[cur][i], u, acc[mt][i], 0, 0, 0);
      }
    }
  }

  // ---- epilogue1: relu(acc + pc1) . Wo; reduce 16 n per lane + 2 shfl -> psum ----
  {
    float4 p4[4], w4[4];
#pragma unroll
    for (int i = 0; i < 4; ++i) {
      int n0 = wc * 64 + i * 16 + hi4 * 4;
      p4[i] = *(const float4*)&pcs[256 + n0];
      w4[i] = ((const float4*)Wo)[(wc * 4 + i) * 4 + hi4];
    }
#pragma unroll
    for (int mt = 0; mt < 4; ++mt) {
      float s = 0.f;
#pragma unroll
      for (int i = 0; i < 4; ++i) {
        s += fmaxf(acc[mt][i][0] + p4[i].x, 0.f) * w4[i].x;
        s += fmaxf(acc[mt][i][1] + p4[i].y, 0.f) * w4[i].y;
        s += fmaxf(acc[mt][i][2] + p4[i].z, 0.f) * w4[i].z;
        s += fmaxf(acc[mt][i][3] + p4[i].w, 0.f) * w4[i].w;
      }
      s += __shfl_xor(s, 16);
      s += __shfl_xor(s, 32);
      if (hi4 == 0) psum[wc * 128 + wr * 64 + mt * 16 + l4] = s;
    }
  }
  __syncthreads();
  if (tid < 128) {
    float s = bo[0] + psum[tid] + psum[128 + tid] + psum[256 + tid] + psum[384 + tid];
    out[row0 + tid] = s;
  }
}

extern "C" void kernel_launch(void* const* d_in, const int* in_sizes, int n_in,
                              void* d_out, int out_size, void* d_ws, size_t ws_size,
                              hipStream_t stream) {
  (void)in_sizes; (void)n_in; (void)out_size; (void)ws_size;
  const float* coords    = (const float*)d_in[0];
  const float* code      = (const float*)d_in[1];
  const float* hs        = (const float*)d_in[2];
  const float* x_statics = (const float*)d_in[3];
  const int*   dir_idx   = (const int*)d_in[4];
  const float* W_mod     = (const float*)d_in[5];
  const float* b_mod     = (const float*)d_in[6];
  const float* W0        = (const float*)d_in[7];
  const float* b0        = (const float*)d_in[8];
  const float* W1        = (const float*)d_in[9];
  const float* b1        = (const float*)d_in[10];
  const float* Wo        = (const float*)d_in[11];
  const float* bo        = (const float*)d_in[12];
  const float* Bmat      = (const float*)d_in[13];
  const float* Ws1       = (const float*)d_in[14];
  const float* bs1       = (const float*)d_in[15];
  const float* Ws2       = (const float*)d_in[16];
  const float* bs2       = (const float*)d_in[17];
  const float* dir_emb   = (const float*)d_in[18];
  float* out = (float*)d_out;
  float* wsf = (float*)d_ws;

  float*    WmT  = wsf + WMT_OFF;
  float*    pc   = wsf + PC_OFF;
  ushort_t* WT0p = (ushort_t*)(wsf + WT0P_OFF);
  ushort_t* WT1p = (ushort_t*)(wsf + WT1P_OFF);

  hipLaunchKernelGGL(pack_mfma_k, dim3(1024), dim3(256), 0, stream,
                     W0, W1, W_mod, WmT, WT0p, WT1p);
  hipLaunchKernelGGL(precompute_pc_k, dim3(1024), dim3(512), 0, stream,
                     code, x_statics, dir_idx, WmT, b_mod, b0, b1,
                     Bmat, Ws1, bs1, Ws2, bs2, dir_emb, pc);
  hipLaunchKernelGGL(film_mfma, dim3(4096), dim3(512), 0, stream,
                     coords, hs, pc, WT0p, WT1p, Wo, bo, out);
}

// Round 8
// 189.266 us; speedup vs baseline: 6.2506x; 1.0203x over previous
//
#include <hip/hip_runtime.h>
#include <math.h>

typedef unsigned short ushort_t;
typedef __bf16 bf16x8 __attribute__((ext_vector_type(8)));
typedef __bf16 bf16x4 __attribute__((ext_vector_type(4)));
typedef float f32x4 __attribute__((ext_vector_type(4)));

#define TWO_PI_F 6.283185307179586f

// ---- ws float-offset layout ----
#define WMT_OFF   0         // [296][512] f32 W_mod^T
#define PC_OFF    151552    // [1024][512] f32 per-b modulation constants
#define WT0P_OFF  675840    // 40960 ushort: GEMM0 W-frags [5 ks][16 nt][64 l][8 j]
#define WT1P_OFF  696320    // 98304 ushort: GEMM1 W-frags [12 ks][16 nt][64 l][8 j]

__device__ __forceinline__ ushort_t f2bf(float f) {
  unsigned int u = __float_as_uint(f);
  u += 0x7fffu + ((u >> 16) & 1u);
  return (ushort_t)(u >> 16);
}

// ---------------- pack: W_mod^T (f32) + MFMA W-fragment panels (bf16) ----------------
__global__ void pack_mfma_k(const float* __restrict__ W0,
                            const float* __restrict__ W1,
                            const float* __restrict__ W_mod,
                            float* __restrict__ WmT,
                            ushort_t* __restrict__ WT0p,
                            ushort_t* __restrict__ WT1p) {
  int i0 = blockIdx.x * blockDim.x + threadIdx.x;
  int stride = gridDim.x * blockDim.x;
  for (int idx = i0; idx < 296 * 512; idx += stride) {
    int c = idx >> 9, m = idx & 511;
    WmT[idx] = W_mod[m * 296 + c];
  }
  for (int e = i0; e < 40960; e += stride) {
    int j = e & 7, l = (e >> 3) & 63, nt = (e >> 9) & 15, ks = e >> 13;
    int k = ks * 32 + (l >> 4) * 8 + j;
    int n = nt * 16 + (l & 15);
    float v = 0.0f;
    if (k < 17) v = W0[n * 17 + k];
    else if (k >= 32) v = W_mod[n * 296 + 128 + (k - 32)];
    WT0p[e] = f2bf(v);
  }
  for (int e = i0; e < 98304; e += stride) {
    int j = e & 7, l = (e >> 3) & 63, nt = (e >> 9) & 15, ks = e >> 13;
    int k = ks * 32 + (l >> 4) * 8 + j;
    int n = nt * 16 + (l & 15);
    float v = (k < 256) ? W1[n * 256 + k]
                        : W_mod[(256 + n) * 296 + 128 + (k - 256)];
    WT1p[e] = f2bf(v);
  }
}

// ---------------- static encoder + per-b modulation consts (verified R1-R7) ----------------
__global__ void precompute_pc_k(const float* __restrict__ code,
                                const float* __restrict__ x_statics,
                                const int* __restrict__ dir_idx,
                                const float* __restrict__ WmT,
                                const float* __restrict__ b_mod,
                                const float* __restrict__ b0,
                                const float* __restrict__ b1,
                                const float* __restrict__ Bmat,
                                const float* __restrict__ Ws1,
                                const float* __restrict__ bs1,
                                const float* __restrict__ Ws2,
                                const float* __restrict__ bs2,
                                const float* __restrict__ dir_emb,
                                float* __restrict__ pc) {
  int b = blockIdx.x, t = threadIdx.x;  // 512 threads
  __shared__ float feats[32];
  __shared__ float h[64];
  __shared__ float se[40];
  __shared__ float cd[128];
  if (t < 16) {
    float p = TWO_PI_F * (x_statics[2 * b] * Bmat[t] + x_statics[2 * b + 1] * Bmat[16 + t]);
    feats[t] = sinf(p);
    feats[16 + t] = cosf(p);
  }
  if (t >= 128 && t < 256) cd[t - 128] = code[b * 128 + (t - 128)];
  __syncthreads();
  if (t < 64) {
    float a = bs1[t];
#pragma unroll
    for (int c = 0; c < 32; ++c) a = fmaf(feats[c], Ws1[t * 32 + c], a);
    h[t] = 0.5f * a * (1.0f + erff(a * 0.70710678118654752440f));
  }
  __syncthreads();
  if (t < 32) {
    float a = bs2[t];
#pragma unroll
    for (int c = 0; c < 64; ++c) a = fmaf(h[c], Ws2[t * 64 + c], a);
    se[t] = a;
  } else if (t < 40) {
    se[t] = dir_emb[dir_idx[b] * 8 + (t - 32)];
  }
  __syncthreads();
  float a = b_mod[t] + ((t < 256) ? b0[t] : b1[t - 256]);
  for (int c = 0; c < 128; ++c) a = fmaf(cd[c], WmT[c * 512 + t], a);
#pragma unroll
  for (int c = 0; c < 40; ++c) a = fmaf(se[c], WmT[(256 + c) * 512 + t], a);
  pc[b * 512 + t] = a;
}

// ---------------- main: MFMA FiLM MLP (R5 structure + weight double-buffer) ----------------
// grid = 8192 (64 rows), block = 512 = 8 waves; LDS 53248 B -> 3 blocks/CU,
// (512,6) -> 84-VGPR cap; R5 measured 40 VGPR so the +16 prefetch regs fit.
// Wave wv owns n-cols [wv*32, wv*32+32); mt 0..3 covers 64 t-rows.
// mfma(W, U): D[n][t]: t = l&15, n = hi4*4 + r.
// rowbuf row (768B), XOR-swizzle ((row&7)<<4) on 16B chunks:
//   GEMM0 k-order {1,2,3,4,0}: pos chunk (bytes [0,64)) read last; barrier;
//   epilogue0 overwrites [0,512) with x0; GEMM1 reads ks*64 for ks=0..11.
// Weight frags double-buffered (named scalars, static indexing): the L2 load
// for step ks+1 issues before step ks's MFMAs; GEMM1's first frag prefetches
// before the epilogue0 barriers (T14 issue-early).
__global__ __launch_bounds__(512, 6) void film_mfma(
    const float* __restrict__ coords, const float* __restrict__ hs,
    const float* __restrict__ pc, const ushort_t* __restrict__ WT0p,
    const ushort_t* __restrict__ WT1p, const float* __restrict__ Wo,
    const float* __restrict__ bo, float* __restrict__ out) {
  __shared__ uint4 rowbuf4[49152 / 16];
  __shared__ float pcs[512];
  __shared__ float psum[512];
  char* rowbuf = (char*)rowbuf4;

  const int tid = threadIdx.x;
  const int wv = tid >> 6;
  const int l = tid & 63;
  const int l4 = l & 15;
  const int hi4 = l >> 4;
  const size_t row0 = (size_t)blockIdx.x * 64;
  const int b = blockIdx.x >> 3;

  pcs[tid] = pc[(size_t)b * 512 + tid];

  // ---- stage hs -> rowbuf[row][512..768), bf16, swizzled ----
  {
    const float4* hsv = (const float4*)(hs + row0 * 128);
#pragma unroll
    for (int it = 0; it < 4; ++it) {
      int idx = it * 512 + tid;
      int r = idx >> 5, c4 = idx & 31;
      float4 v = hsv[idx];
      bf16x4 hb;
      hb[0] = (__bf16)v.x; hb[1] = (__bf16)v.y;
      hb[2] = (__bf16)v.z; hb[3] = (__bf16)v.w;
      int byte = (r * 768 + 512 + c4 * 8) ^ ((r & 7) << 4);
      *(uint2*)(rowbuf + byte) = __builtin_bit_cast(uint2, hb);
    }
  }
  // ---- stage pos -> rowbuf[row][0..64), bf16, pre-swizzled 16B chunks ----
  if (tid < 64) {
    int row = tid;
    float c = coords[row0 + row];
    __bf16 pv[32];
    pv[0] = (__bf16)c;
    pv[1] = (__bf16)0.0f;  // sin(0*c)
    pv[9] = (__bf16)1.0f;  // cos(0*c)
#pragma unroll
    for (int f = 1; f < 8; ++f) {
      float s, co;
      __sincosf(1.25f * (float)f * c, &s, &co);
      pv[1 + f] = (__bf16)s;
      pv[9 + f] = (__bf16)co;
    }
#pragma unroll
    for (int k = 17; k < 32; ++k) pv[k] = (__bf16)0.0f;
    int base = row * 768, swzp = (row & 7) << 4;
#pragma unroll
    for (int s = 0; s < 4; ++s)
      *(uint4*)(rowbuf + ((base + s * 16) ^ swzp)) = *(const uint4*)&pv[s * 8];
  }

  // per-mt LDS addressing
  int addrU[4], swzU[4];
#pragma unroll
  for (int mt = 0; mt < 4; ++mt) {
    int row = mt * 16 + l4;
    addrU[mt] = row * 768 + hi4 * 16;
    swzU[mt] = (row & 7) << 4;
  }

  const uint4* Bb0 = (const uint4*)WT0p;
  const uint4* Bb1 = (const uint4*)WT1p;

  // prefetch GEMM0 step 0 (ks=1) weights before the staging barrier
  uint4 wp0 = Bb0[(1 * 16 + wv * 2 + 0) * 64 + l];
  uint4 wp1 = Bb0[(1 * 16 + wv * 2 + 1) * 64 + l];

  __syncthreads();

  f32x4 acc[4][2];
#pragma unroll
  for (int mt = 0; mt < 4; ++mt)
#pragma unroll
    for (int i = 0; i < 2; ++i) acc[mt][i] = (f32x4){0.f, 0.f, 0.f, 0.f};

  // ---------------- GEMM0: K=160, k-chunk order {1,2,3,4,0}, W double-buffered ----------------
#pragma unroll
  for (int kk = 0; kk < 5; ++kk) {
    const int ks = (kk < 4) ? (kk + 1) : 0;
    bf16x8 w0 = __builtin_bit_cast(bf16x8, wp0);
    bf16x8 w1 = __builtin_bit_cast(bf16x8, wp1);
    if (kk < 4) {
      const int ksn = (kk < 3) ? (kk + 2) : 0;
      wp0 = Bb0[(ksn * 16 + wv * 2 + 0) * 64 + l];
      wp1 = Bb0[(ksn * 16 + wv * 2 + 1) * 64 + l];
    }
#pragma unroll
    for (int mt = 0; mt < 4; ++mt) {
      bf16x8 u;
      int off = (ks == 0) ? addrU[mt] : (addrU[mt] + 512 + (ks - 1) * 64);
      __builtin_memcpy(&u, rowbuf + (off ^ swzU[mt]), 16);
      acc[mt][0] = __builtin_amdgcn_mfma_f32_16x16x32_bf16(w0, u, acc[mt][0], 0, 0, 0);
      acc[mt][1] = __builtin_amdgcn_mfma_f32_16x16x32_bf16(w1, u, acc[mt][1], 0, 0, 0);
    }
  }

  // prefetch GEMM1 step 0 weights; they land during epilogue0 + barriers
  wp0 = Bb1[(wv * 2 + 0) * 64 + l];
  wp1 = Bb1[(wv * 2 + 1) * 64 + l];

  __syncthreads();  // all pos reads done before x0 overwrites [0,512)

  // ---- epilogue0: relu(acc + pc0) -> x0 bf16, packed b64 writes ----
#pragma unroll
  for (int i = 0; i < 2; ++i) {
    int n0 = (wv * 2 + i) * 16 + hi4 * 4;
    float4 p4 = *(const float4*)&pcs[n0];
#pragma unroll
    for (int mt = 0; mt < 4; ++mt) {
      int t = mt * 16 + l4;
      bf16x4 hv;
      hv[0] = (__bf16)fmaxf(acc[mt][i][0] + p4.x, 0.f);
      hv[1] = (__bf16)fmaxf(acc[mt][i][1] + p4.y, 0.f);
      hv[2] = (__bf16)fmaxf(acc[mt][i][2] + p4.z, 0.f);
      hv[3] = (__bf16)fmaxf(acc[mt][i][3] + p4.w, 0.f);
      int byte = (t * 768 + n0 * 2) ^ ((t & 7) << 4);
      *(uint2*)(rowbuf + byte) = __builtin_bit_cast(uint2, hv);
    }
  }
  __syncthreads();

#pragma unroll
  for (int mt = 0; mt < 4; ++mt)
#pragma unroll
    for (int i = 0; i < 2; ++i) acc[mt][i] = (f32x4){0.f, 0.f, 0.f, 0.f};

  // ---------------- GEMM1: K=384 (x0 [0,512) then hs [512,768)), W double-buffered ----------------
#pragma unroll
  for (int ks = 0; ks < 12; ++ks) {
    bf16x8 w0 = __builtin_bit_cast(bf16x8, wp0);
    bf16x8 w1 = __builtin_bit_cast(bf16x8, wp1);
    if (ks < 11) {
      wp0 = Bb1[((ks + 1) * 16 + wv * 2 + 0) * 64 + l];
      wp1 = Bb1[((ks + 1) * 16 + wv * 2 + 1) * 64 + l];
    }
#pragma unroll
    for (int mt = 0; mt < 4; ++mt) {
      bf16x8 u;
      __builtin_memcpy(&u, rowbuf + ((addrU[mt] + ks * 64) ^ swzU[mt]), 16);
      acc[mt][0] = __builtin_amdgcn_mfma_f32_16x16x32_bf16(w0, u, acc[mt][0], 0, 0, 0);
      acc[mt][1] = __builtin_amdgcn_mfma_f32_16x16x32_bf16(w1, u, acc[mt][1], 0, 0, 0);
    }
  }

  // ---- epilogue1: relu(acc + pc1) . Wo; in-reg n-reduce + 2 shfl -> psum ----
  {
    float4 p4[2], w4[2];
#pragma unroll
    for (int i = 0; i < 2; ++i) {
      int n0 = (wv * 2 + i) * 16 + hi4 * 4;
      p4[i] = *(const float4*)&pcs[256 + n0];
      w4[i] = ((const float4*)Wo)[(wv * 2 + i) * 4 + hi4];
    }
#pragma unroll
    for (int mt = 0; mt < 4; ++mt) {
      float s = 0.f;
#pragma unroll
      for (int i = 0; i < 2; ++i) {
        s += fmaxf(acc[mt][i][0] + p4[i].x, 0.f) * w4[i].x;
        s += fmaxf(acc[mt][i][1] + p4[i].y, 0.f) * w4[i].y;
        s += fmaxf(acc[mt][i][2] + p4[i].z, 0.f) * w4[i].z;
        s += fmaxf(acc[mt][i][3] + p4[i].w, 0.f) * w4[i].w;
      }
      s += __shfl_xor(s, 16);
      s += __shfl_xor(s, 32);
      if (hi4 == 0) psum[wv * 64 + mt * 16 + l4] = s;
    }
  }
  __syncthreads();
  if (tid < 64) {
    float s = bo[0];
#pragma unroll
    for (int w = 0; w < 8; ++w) s += psum[w * 64 + tid];
    out[row0 + tid] = s;
  }
}

extern "C" void kernel_launch(void* const* d_in, const int* in_sizes, int n_in,
                              void* d_out, int out_size, void* d_ws, size_t ws_size,
                              hipStream_t stream) {
  (void)in_sizes; (void)n_in; (void)out_size; (void)ws_size;
  const float* coords    = (const float*)d_in[0];
  const float* code      = (const float*)d_in[1];
  const float* hs        = (const float*)d_in[2];
  const float* x_statics = (const float*)d_in[3];
  const int*   dir_idx   = (const int*)d_in[4];
  const float* W_mod     = (const float*)d_in[5];
  const float* b_mod     = (const float*)d_in[6];
  const float* W0        = (const float*)d_in[7];
  const float* b0        = (const float*)d_in[8];
  const float* W1        = (const float*)d_in[9];
  const float* b1        = (const float*)d_in[10];
  const float* Wo        = (const float*)d_in[11];
  const float* bo        = (const float*)d_in[12];
  const float* Bmat      = (const float*)d_in[13];
  const float* Ws1       = (const float*)d_in[14];
  const float* bs1       = (const float*)d_in[15];
  const float* Ws2       = (const float*)d_in[16];
  const float* bs2       = (const float*)d_in[17];
  const float* dir_emb   = (const float*)d_in[18];
  float* out = (float*)d_out;
  float* wsf = (float*)d_ws;

  float*    WmT  = wsf + WMT_OFF;
  float*    pc   = wsf + PC_OFF;
  ushort_t* WT0p = (ushort_t*)(wsf + WT0P_OFF);
  ushort_t* WT1p = (ushort_t*)(wsf + WT1P_OFF);

  hipLaunchKernelGGL(pack_mfma_k, dim3(1024), dim3(256), 0, stream,
                     W0, W1, W_mod, WmT, WT0p, WT1p);
  hipLaunchKernelGGL(precompute_pc_k, dim3(1024), dim3(512), 0, stream,
                     code, x_statics, dir_idx, WmT, b_mod, b0, b1,
                     Bmat, Ws1, bs1, Ws2, bs2, dir_emb, pc);
  hipLaunchKernelGGL(film_mfma, dim3(8192), dim3(512), 0, stream,
                     coords, hs, pc, WT0p, WT1p, Wo, bo, out);
}